// Round 20
// baseline (124.020 us; speedup 1.0000x reference)
//
#include <hip/hip_runtime.h>

#define BATCH 256
#define SEQ 2048
#define NT 48
#define START_TAG 46
#define END_TAG 47
#define LN2f  0.6931471805599453f

// ws layout
#define TAF16 0        // K16 A-frags exp(trans) bf16: [9][64] x 8B  = 4608
#define TAF32 4608     // K32 A-frags (contig8): [3 I][2 Kc][64] x 16B = 6144
#define TBF   10752    // B-frag exp(trans) f32: [9][64] x 16B       = 9216
#define TFLAG 19968    // u32: 1 = K32 (A contig8 + B concat) validated
#define TCUM  20480    // prefix sums: int cum[257]                  = 1028
#define TSC   24576    // per-chunk log2 scales: [B][64] f32         = 64KiB
#define TW    131072   // chunk matrices bf16: [B][64][48][48]
                       //   c < h : M row-major; c >= h: M^T row-major

typedef float v2f __attribute__((ext_vector_type(2)));
typedef float v4f __attribute__((ext_vector_type(4)));
typedef short s16x4 __attribute__((ext_vector_type(4)));
typedef short s16x8 __attribute__((ext_vector_type(8)));
typedef unsigned int u32;
typedef unsigned short u16;
typedef u32 u32x2 __attribute__((ext_vector_type(2)));
typedef u32 u32x4 __attribute__((ext_vector_type(4)));

__device__ __forceinline__ u32 pkbf(float a, float b) {
    u32 r;
    asm("v_cvt_pk_bf16_f32 %0, %1, %2" : "=v"(r) : "v"(a), "v"(b));
    return r;
}
__device__ __forceinline__ float bflo(u32 w) { return __builtin_bit_cast(float, w << 16); }
__device__ __forceinline__ float bfhi(u32 w) { return __builtin_bit_cast(float, w & 0xffff0000u); }

__device__ __forceinline__ float rfl(float x) {
    return __builtin_bit_cast(float,
        __builtin_amdgcn_readfirstlane(__builtin_bit_cast(int, x)));
}

__device__ __forceinline__ v4f mfma16_z(s16x4 a, s16x4 b, v4f z) {
    v4f d;
    asm volatile("v_mfma_f32_16x16x16_bf16 %0, %2, %3, %1"
                 : "=&v"(d) : "v"(z), "v"(a), "v"(b));
    return d;
}
__device__ __forceinline__ void mfma16_acc(v4f& acc, s16x4 a, s16x4 b) {
    asm volatile("v_mfma_f32_16x16x16_bf16 %0, %1, %2, %0"
                 : "+v"(acc) : "v"(a), "v"(b));
}
__device__ __forceinline__ v4f mfma32_z(s16x8 a, s16x8 b, v4f z) {
    v4f d;
    asm volatile("v_mfma_f32_16x16x32_bf16 %0, %2, %3, %1"
                 : "=&v"(d) : "v"(z), "v"(a), "v"(b));
    return d;
}
__device__ __forceinline__ void mfma32_acc(v4f& acc, s16x8 a, s16x8 b) {
    asm volatile("v_mfma_f32_16x16x32_bf16 %0, %1, %2, %0"
                 : "+v"(acc) : "v"(a), "v"(b));
}

// ======================= shared step/init functions =======================
// State semantics (proven r7-r19): M bf16 in C layout; per step acc = E*M,
// gn = raw P00; M' = acc .* (em * 1/gn_prev); Lc += log2(gn) lagged.

__device__ __forceinline__ void k16_init(s16x4 (&mw)[3][3], const v4f (&bfv)[9],
                                         const v4f (&em)[3]) {
    #pragma unroll
    for (int K = 0; K < 3; ++K)
        #pragma unroll
        for (int J = 0; J < 3; ++J) {
            v4f sc = bfv[K * 3 + J] * em[K];
            mw[K][J] = __builtin_bit_cast(s16x4,
                (u32x2){pkbf(sc.x, sc.y), pkbf(sc.z, sc.w)});
        }
}

__device__ __forceinline__ void k16_step(s16x4 (&mw)[3][3], const s16x4 (&aw)[3][3],
                                         const v4f (&em)[3],
                                         float& Lc, float& lg, float& s) {
    const v4f kz = {0.f, 0.f, 0.f, 0.f};
    v4f acc[3][3];
    #pragma unroll
    for (int I = 0; I < 3; ++I)
        #pragma unroll
        for (int J = 0; J < 3; ++J)
            acc[I][J] = mfma16_z(aw[I][0], mw[0][J], kz);
    #pragma unroll
    for (int I = 0; I < 3; ++I)
        #pragma unroll
        for (int J = 0; J < 3; ++J)
            mfma16_acc(acc[I][J], aw[I][1], mw[1][J]);
    #pragma unroll
    for (int I = 0; I < 3; ++I)
        #pragma unroll
        for (int J = 0; J < 3; ++J)
            mfma16_acc(acc[I][J], aw[I][2], mw[2][J]);
    asm volatile("s_nop 7\n\ts_nop 7");
    __builtin_amdgcn_sched_barrier(0);

    const float gn = rfl(acc[0][0].x);
    Lc += lg;
    #pragma unroll
    for (int K = 0; K < 3; ++K) {
        v4f sp = em[K] * s;
        #pragma unroll
        for (int J = 0; J < 3; ++J) {
            v4f sc = acc[K][J] * sp;
            mw[K][J] = __builtin_bit_cast(s16x4,
                (u32x2){pkbf(sc.x, sc.y), pkbf(sc.z, sc.w)});
        }
    }
    lg = __log2f(gn);
    s  = __builtin_amdgcn_rcpf(gn);
}

// K32: B operand = concat of K16 halves (C-derived P/Q, zero-shuffle feed);
// A operand = contig8 hypothesis, packed at setup.
__device__ __forceinline__ void k32_init(u32x4 (&P)[3], u32x4 (&Q)[3],
                                         const v4f (&bfv)[9], const v4f (&em)[3]) {
    #pragma unroll
    for (int J = 0; J < 3; ++J) {
        v4f s0 = bfv[0 * 3 + J] * em[0];
        v4f s1 = bfv[1 * 3 + J] * em[1];
        v4f s2 = bfv[2 * 3 + J] * em[2];
        P[J] = (u32x4){pkbf(s0.x, s0.y), pkbf(s0.z, s0.w),
                       pkbf(s1.x, s1.y), pkbf(s1.z, s1.w)};
        u32 a2 = pkbf(s2.x, s2.y), b2 = pkbf(s2.z, s2.w);
        Q[J] = (u32x4){a2, b2, a2, b2};
    }
}

__device__ __forceinline__ void k32_step(u32x4 (&P)[3], u32x4 (&Q)[3],
                                         const s16x8 (&aw)[3][2], const v4f (&em)[3],
                                         float& Lc, float& lg, float& s) {
    const v4f kz = {0.f, 0.f, 0.f, 0.f};
    v4f acc[3][3];
    #pragma unroll
    for (int I = 0; I < 3; ++I)
        #pragma unroll
        for (int J = 0; J < 3; ++J)
            acc[I][J] = mfma32_z(aw[I][0], __builtin_bit_cast(s16x8, P[J]), kz);
    #pragma unroll
    for (int I = 0; I < 3; ++I)
        #pragma unroll
        for (int J = 0; J < 3; ++J)
            mfma32_acc(acc[I][J], aw[I][1], __builtin_bit_cast(s16x8, Q[J]));
    asm volatile("s_nop 7\n\ts_nop 7");
    __builtin_amdgcn_sched_barrier(0);

    const float gn = rfl(acc[0][0].x);
    Lc += lg;
    v4f sp0 = em[0] * s, sp1 = em[1] * s, sp2 = em[2] * s;
    #pragma unroll
    for (int J = 0; J < 3; ++J) {
        v4f s0 = acc[0][J] * sp0;
        v4f s1 = acc[1][J] * sp1;
        v4f s2 = acc[2][J] * sp2;
        P[J] = (u32x4){pkbf(s0.x, s0.y), pkbf(s0.z, s0.w),
                       pkbf(s1.x, s1.y), pkbf(s1.z, s1.w)};
        u32 a2 = pkbf(s2.x, s2.y), b2 = pkbf(s2.z, s2.w);
        Q[J] = (u32x4){a2, b2, a2, b2};
    }
    lg = __log2f(gn);
    s  = __builtin_amdgcn_rcpf(gn);
}

__device__ __forceinline__ bool near2(u32 a, u32 b) {
    float al = bflo(a), ah = bfhi(a), bl = bflo(b), bh = bfhi(b);
    bool o1 = fabsf(al - bl) <= 0.08f * fmaxf(fabsf(al), fabsf(bl)) + 1e-4f;
    bool o2 = fabsf(ah - bh) <= 0.08f * fmaxf(fabsf(ah), fabsf(bh)) + 1e-4f;
    return o1 && o2;
}

// ---------------------------------------------------------------------------
// Kernel 0: fragments + prefix sums + PROBE.
// K32 A-frag hypothesis (contig8): lane l supplies A[i][k], i = l&15,
// k = 8*(l>>4)+q (q=0..7) for Kc=0 (k=0..31); k = 32+8*(l>>4)+q for Kc=1
// (zero for k>=48).  B stays concat (m162 tr_b16-derived; enables the
// zero-shuffle C->B feed).  Probe: 4-step K16 vs K32 chain on synthetic
// data; all-lane ballot -> flag.
// ---------------------------------------------------------------------------
__global__ void __launch_bounds__(64)
crf_setup(const float* __restrict__ trans, const int* __restrict__ seqlen,
          void* ws) {
    __shared__ float el[NT * NT];
    const int lane = threadIdx.x, ln = lane & 15, g = lane >> 4;
    #pragma unroll
    for (int m = 0; m < 36; ++m) {
        int idx = lane + 64 * m;
        el[idx] = __expf(trans[idx]);
    }
    u32x2* AF   = (u32x2*)((char*)ws + TAF16);
    u32x4* AW32 = (u32x4*)((char*)ws + TAF32);
    v4f*   BF   = (v4f*)((char*)ws + TBF);

    s16x4 aw16[3][3];
    s16x8 aw32[3][2];
    #pragma unroll
    for (int I = 0; I < 3; ++I) {
        const int r = I * 16 + ln;
        #pragma unroll
        for (int K = 0; K < 3; ++K) {
            const v4f ev = *(const v4f*)&el[r * NT + K * 16 + g * 4];
            u32x2 w = (u32x2){pkbf(ev.x, ev.y), pkbf(ev.z, ev.w)};
            AF[(I * 3 + K) * 64 + lane] = w;
            aw16[I][K] = __builtin_bit_cast(s16x4, w);
        }
        // contig8 A-frags
        u32x4 w0, w1;
        #pragma unroll
        for (int p = 0; p < 4; ++p) {
            const int k0 = 8 * g + 2 * p;            // 0..31
            w0[p] = pkbf(el[r * NT + k0], el[r * NT + k0 + 1]);
            const int k1 = 32 + 8 * g + 2 * p;       // 32..63
            float a = (k1 < NT)     ? el[r * NT + k1]     : 0.f;
            float b = (k1 + 1 < NT) ? el[r * NT + k1 + 1] : 0.f;
            w1[p] = pkbf(a, b);
        }
        AW32[(I * 2 + 0) * 64 + lane] = w0;
        AW32[(I * 2 + 1) * 64 + lane] = w1;
        aw32[I][0] = __builtin_bit_cast(s16x8, w0);
        aw32[I][1] = __builtin_bit_cast(s16x8, w1);
    }
    v4f bfv[9];
    #pragma unroll
    for (int K = 0; K < 3; ++K)
        #pragma unroll
        for (int J = 0; J < 3; ++J) {
            v4f v;
            #pragma unroll
            for (int i = 0; i < 4; ++i)
                v[i] = el[(K * 16 + g * 4 + i) * NT + J * 16 + ln];
            BF[(K * 3 + J) * 64 + lane] = v;
            bfv[K * 3 + J] = v;
        }

    // ---- probe: 4-step mini-chain K16 vs K32, synthetic positive emissions
    v4f em[3];
    auto synth = [&](int t, v4f (&e)[3]) {
        #pragma unroll
        for (int K = 0; K < 3; ++K)
            #pragma unroll
            for (int i = 0; i < 4; ++i) {
                int row = K * 16 + g * 4 + i;
                e[K][i] = el[(unsigned)(t * 131 + row * 7) % (NT * NT)] + 0.5f;
            }
    };
    s16x4 m16[3][3];
    u32x4 P[3], Q[3];
    synth(0, em);
    k16_init(m16, bfv, em);
    k32_init(P, Q, bfv, em);
    float Lc16 = 0.f, lg16 = 0.f, s16s = 1.f;
    float Lc32 = 0.f, lg32 = 0.f, s32s = 1.f;
    for (int t = 1; t <= 4; ++t) { synth(t, em); k16_step(m16, aw16, em, Lc16, lg16, s16s); }
    for (int t = 1; t <= 4; ++t) { synth(t, em); k32_step(P, Q, aw32, em, Lc32, lg32, s32s); }

    bool ok = fabsf(Lc16 - Lc32) <= 0.2f;
    #pragma unroll
    for (int J = 0; J < 3; ++J) {
        u32x2 w0 = __builtin_bit_cast(u32x2, m16[0][J]);
        u32x2 w1 = __builtin_bit_cast(u32x2, m16[1][J]);
        u32x2 w2 = __builtin_bit_cast(u32x2, m16[2][J]);
        ok = ok && near2(w0.x, P[J].x) && near2(w0.y, P[J].y);
        ok = ok && near2(w1.x, P[J].z) && near2(w1.y, P[J].w);
        ok = ok && near2(w2.x, Q[J].x) && near2(w2.y, Q[J].y);
    }
    unsigned long long vote = __ballot(ok);
    if (lane == 0)
        *((u32*)((char*)ws + TFLAG)) = (vote == 0xFFFFFFFFFFFFFFFFull) ? 1u : 0u;

    if (lane == 0) {
        int* cum = (int*)((char*)ws + TCUM);
        int acc = 0;
        for (int b = 0; b < BATCH; ++b) {
            cum[b] = acc;
            int L = seqlen[b];
            if (L < 1) L = 1;
            if (L > SEQ) L = SEQ;
            acc += (L + 31) >> 5;
        }
        cum[BATCH] = acc;
    }
}

// ---------------------------------------------------------------------------
// Kernel 1 (hybrid, compacted): wave widx handles the widx-th ACTIVE chunk.
// Wave-uniform branch on the HW probe flag: K32 path (18 MFMA/step, ~5-8cyc
// pipe each — removes the 450cyc/step K16 MFMA-pipe bottleneck identified
// from MfmaUtil across r13-r19) vs the proven K16 path.
// __launch_bounds__(256,4): cap 128 — the only spill-free point (r14/16/19).
// Store direction-aware for split phase2 (c<h: M row-major, else M^T).
// ---------------------------------------------------------------------------
__global__ void __launch_bounds__(256, 4)
crf_phase1h(const float* __restrict__ feat, const int* __restrict__ seqlen,
            void* __restrict__ ws) {
    const int wid = threadIdx.x >> 6;
    const int widx = blockIdx.x * 4 + wid;
    const int* cum = (const int*)((const char*)ws + TCUM);
    if (widx >= cum[BATCH]) return;

    int lo = 0, hi = BATCH;
    #pragma unroll
    for (int it = 0; it < 8; ++it) {
        int mid = (lo + hi) >> 1;
        if (cum[mid] <= widx) lo = mid; else hi = mid;
    }
    const int b = lo;
    const int c = widx - cum[b];
    const int t0 = c * 32;
    int Lraw = seqlen[b];
    if (Lraw < 1) Lraw = 1;
    if (Lraw > SEQ) Lraw = SEQ;
    const int nbS = (Lraw + 31) >> 5;
    const int half = nbS >> 1;
    int n = Lraw - t0;
    if (n > 32) n = 32;

    const int lane = threadIdx.x & 63, ln = lane & 15, g = lane >> 4;

    __shared__ v4f flv[4][32 * 12];
    v4f* fl = flv[wid];

    const u32 flag = *(const u32*)((const char*)ws + TFLAG);

    // stage rows t0..t0+31 (in-bounds), exp() applied once
    {
        const v4f* fg = (const v4f*)(feat + ((size_t)b * SEQ + t0) * NT);
        #pragma unroll
        for (int m = 0; m < 6; ++m) {
            v4f v = fg[m * 64 + lane];
            v4f e;
            #pragma unroll
            for (int i = 0; i < 4; ++i) e[i] = __expf(v[i]);
            fl[m * 64 + lane] = e;
        }
    }

    v4f em[3];
    #pragma unroll
    for (int K = 0; K < 3; ++K) em[K] = fl[K * 4 + g];

    float Lc = 0.f, lg = 0.f, s = 1.f;
    char* wb = (char*)ws + TW + ((size_t)(b * 64 + c)) * 4608;
    const v4f* BF = (const v4f*)((const char*)ws + TBF);

    if (flag) {
        // ---- K32 fast path
        s16x8 aw[3][2];
        const u32x4* AW = (const u32x4*)((const char*)ws + TAF32);
        #pragma unroll
        for (int I = 0; I < 3; ++I)
            #pragma unroll
            for (int Kc = 0; Kc < 2; ++Kc)
                aw[I][Kc] = __builtin_bit_cast(s16x8, AW[(I * 2 + Kc) * 64 + lane]);
        u32x4 P[3], Q[3];
        {
            v4f bfv[9];
            #pragma unroll
            for (int q = 0; q < 9; ++q) bfv[q] = BF[q * 64 + lane];
            k32_init(P, Q, bfv, em);
        }
        for (int t = 1; t < n; ++t) {
            #pragma unroll
            for (int K = 0; K < 3; ++K) em[K] = fl[t * 12 + K * 4 + g];
            k32_step(P, Q, aw, em, Lc, lg, s);
        }
        // store: P[J] = rows {4g..4g+3}(t0), {16+4g..}(t1); Q[J] = {32+4g..}
        if (c >= half) {
            #pragma unroll
            for (int J = 0; J < 3; ++J) {
                const int col = J * 16 + ln;
                *(u32*)(wb + 2 * (col * NT + 4 * g))          = P[J].x;
                *(u32*)(wb + 2 * (col * NT + 4 * g + 2))      = P[J].y;
                *(u32*)(wb + 2 * (col * NT + 16 + 4 * g))     = P[J].z;
                *(u32*)(wb + 2 * (col * NT + 16 + 4 * g + 2)) = P[J].w;
                *(u32*)(wb + 2 * (col * NT + 32 + 4 * g))     = Q[J].x;
                *(u32*)(wb + 2 * (col * NT + 32 + 4 * g + 2)) = Q[J].y;
            }
        } else {
            u16* mb = (u16*)wb;
            #pragma unroll
            for (int J = 0; J < 3; ++J) {
                const int col = J * 16 + ln;
                u32 v;
                v = P[J].x;
                mb[(4 * g + 0) * NT + col] = (u16)(v & 0xffff);
                mb[(4 * g + 1) * NT + col] = (u16)(v >> 16);
                v = P[J].y;
                mb[(4 * g + 2) * NT + col] = (u16)(v & 0xffff);
                mb[(4 * g + 3) * NT + col] = (u16)(v >> 16);
                v = P[J].z;
                mb[(16 + 4 * g + 0) * NT + col] = (u16)(v & 0xffff);
                mb[(16 + 4 * g + 1) * NT + col] = (u16)(v >> 16);
                v = P[J].w;
                mb[(16 + 4 * g + 2) * NT + col] = (u16)(v & 0xffff);
                mb[(16 + 4 * g + 3) * NT + col] = (u16)(v >> 16);
                v = Q[J].x;
                mb[(32 + 4 * g + 0) * NT + col] = (u16)(v & 0xffff);
                mb[(32 + 4 * g + 1) * NT + col] = (u16)(v >> 16);
                v = Q[J].y;
                mb[(32 + 4 * g + 2) * NT + col] = (u16)(v & 0xffff);
                mb[(32 + 4 * g + 3) * NT + col] = (u16)(v >> 16);
            }
        }
    } else {
        // ---- proven K16 path
        s16x4 aw[3][3];
        const u32x2* AF = (const u32x2*)((const char*)ws + TAF16);
        #pragma unroll
        for (int I = 0; I < 3; ++I)
            #pragma unroll
            for (int K = 0; K < 3; ++K)
                aw[I][K] = __builtin_bit_cast(s16x4, AF[(I * 3 + K) * 64 + lane]);
        s16x4 mw[3][3];
        {
            v4f bfv[9];
            #pragma unroll
            for (int q = 0; q < 9; ++q) bfv[q] = BF[q * 64 + lane];
            k16_init(mw, bfv, em);
        }
        for (int t = 1; t < n; ++t) {
            #pragma unroll
            for (int K = 0; K < 3; ++K) em[K] = fl[t * 12 + K * 4 + g];
            k16_step(mw, aw, em, Lc, lg, s);
        }
        if (c >= half) {
            #pragma unroll
            for (int K = 0; K < 3; ++K)
                #pragma unroll
                for (int J = 0; J < 3; ++J) {
                    u32x2 w = __builtin_bit_cast(u32x2, mw[K][J]);
                    *(u32*)(wb + 2 * ((J * 16 + ln) * NT + K * 16 + g * 4))     = w.x;
                    *(u32*)(wb + 2 * ((J * 16 + ln) * NT + K * 16 + g * 4 + 2)) = w.y;
                }
        } else {
            u16* mb = (u16*)wb;
            #pragma unroll
            for (int K = 0; K < 3; ++K)
                #pragma unroll
                for (int J = 0; J < 3; ++J) {
                    u32x2 w = __builtin_bit_cast(u32x2, mw[K][J]);
                    const int r0 = K * 16 + g * 4, col = J * 16 + ln;
                    mb[(r0 + 0) * NT + col] = (u16)(w.x & 0xffff);
                    mb[(r0 + 1) * NT + col] = (u16)(w.x >> 16);
                    mb[(r0 + 2) * NT + col] = (u16)(w.y & 0xffff);
                    mb[(r0 + 3) * NT + col] = (u16)(w.y >> 16);
                }
        }
    }
    if (lane == 0)
        ((float*)((char*)ws + TSC))[b * 64 + c] = Lc;
}

// ---------------------------------------------------------------------------
// Kernel 2 (split, r18-proven): 128 threads/sample.
// wave0: a^T <- a^T M_c, c = nb-1..h (M^T rows); wave1: b <- M_c b, c=0..h-1
// (M rows).  out = ln2*(Da + Db + log2(a . b)).
// ---------------------------------------------------------------------------
__global__ void __launch_bounds__(128)
crf_phase2s(const float* __restrict__ trans, const int* __restrict__ seqlen,
            const void* __restrict__ ws, float* __restrict__ out) {
    const int b = blockIdx.x;
    const int wave = threadIdx.x >> 6;
    const int lane = threadIdx.x & 63;
    const int j = (lane < NT) ? lane : (lane - 16);

    __shared__ v4f hsv[2][12];
    __shared__ float sres[2][NT];
    __shared__ float sD[2];
    float* hs = (float*)hsv[wave];

    int L = seqlen[b];
    if (L < 1) L = 1;
    if (L > SEQ) L = SEQ;
    const int nb = (L + 31) >> 5;
    const int half = nb >> 1;
    const float* sc = (const float*)((const char*)ws + TSC) + b * 64;
    const char* wbase = (const char*)ws + TW + (size_t)b * 64 * 4608;

    const int c0 = wave ? 0 : (nb - 1);
    const int cstep = wave ? 1 : -1;
    const int nhops = wave ? half : (nb - half);

    float q = wave ? ((j == START_TAG) ? 1.f : 0.f)
                   : __expf(trans[END_TAG * NT + j]);
    float D = 0.f;

    if (nhops > 0) {
        u32x4 buf[6];
        {
            const u32x4* wr = (const u32x4*)(wbase + (size_t)c0 * 4608 + j * 96);
            #pragma unroll
            for (int m = 0; m < 6; ++m) buf[m] = wr[m];
        }
        for (int hh = 0; hh < nhops; ++hh) {
            const int c = c0 + hh * cstep;
            u32x4 cur[6];
            #pragma unroll
            for (int m = 0; m < 6; ++m) cur[m] = buf[m];
            if (hh + 1 < nhops) {
                const u32x4* wr =
                    (const u32x4*)(wbase + (size_t)(c + cstep) * 4608 + j * 96);
                #pragma unroll
                for (int m = 0; m < 6; ++m) buf[m] = wr[m];
            }

            if (lane < NT) hs[lane] = q;
            v4f hq[12];
            #pragma unroll
            for (int k = 0; k < 12; ++k) hq[k] = hsv[wave][k];
            const float h0 = hq[0][0];

            v2f a = {0.f, 0.f};
            #pragma unroll
            for (int m = 0; m < 6; ++m) {
                #pragma unroll
                for (int p = 0; p < 4; ++p) {
                    const int i = 2 * (4 * m + p);
                    u32 wv = cur[m][p];
                    v2f wp;
                    wp.x = bflo(wv);
                    wp.y = bfhi(wv);
                    v2f up = { hq[i >> 2][i & 3], hq[i >> 2][(i & 3) + 1] };
                    a += wp * up;
                }
            }
            const float dot = a.x + a.y;
            const bool ok = (h0 > 0.f);
            q = ok ? dot * __builtin_amdgcn_rcpf(h0) : dot;
            D += (ok ? __log2f(h0) : 0.f) + sc[c];
        }
    }

    if (lane < NT) sres[wave][j] = q;
    if (lane == 0) sD[wave] = D;
    __syncthreads();

    if (wave == 0) {
        float term = (lane < NT) ? sres[0][lane] * sres[1][lane] : 0.f;
        #pragma unroll
        for (int m = 32; m >= 1; m >>= 1) term += __shfl_xor(term, m, 64);
        if (lane == 0)
            out[b] = LN2f * (sD[0] + sD[1] + __log2f(term));
    }
}

// ---------------------------------------------------------------------------
// Fallback: proven round-2 scalar kernel (ws too small)
// ---------------------------------------------------------------------------
__global__ void __launch_bounds__(64)
crf_scalar(const float* __restrict__ features, const float* __restrict__ transitions,
           const int* __restrict__ seq_len, float* __restrict__ out) {
    const int b = blockIdx.x;
    const int lane = threadIdx.x;
    const int j = (lane < NT) ? lane : (lane - 16);
    __shared__ v4f hs4[NT / 4];
    float* hs = (float*)hs4;

    v2f E2[NT / 2];
    {
        const v4f* trow = (const v4f*)(transitions + j * NT);
        #pragma unroll
        for (int k = 0; k < NT / 4; ++k) {
            v4f tv = trow[k];
            E2[2 * k].x = __expf(tv.x); E2[2 * k].y = __expf(tv.y);
            E2[2 * k + 1].x = __expf(tv.z); E2[2 * k + 1].y = __expf(tv.w);
        }
    }
    const float Eend = __expf(transitions[END_TAG * NT + j]);
    const int L = seq_len[b];
    const float* fbase = features + ((size_t)b * SEQ) * NT + j;

    float q = E2[START_TAG / 2].x * __expf(fbase[0]);
    float Clog2 = 0.0f;
    if (lane < NT) hs[lane] = q;

    float fb[8];
    #pragma unroll
    for (int u = 0; u < 8; ++u) {
        int tp = 1 + u;
        fb[u] = fbase[(size_t)(tp < SEQ ? tp : 0) * NT];
    }

    auto STEP = [&](float femit) {
        v4f hq[NT / 4];
        #pragma unroll
        for (int k = 0; k < NT / 4; ++k) hq[k] = hs4[k];
        float h0 = hq[0].x;
        float r = __builtin_amdgcn_rcpf(h0);
        float e = __expf(femit);
        float re = r * e;
        v2f a0 = {0.f, 0.f}, a1 = {0.f, 0.f};
        #pragma unroll
        for (int k = 0; k < NT / 4; ++k) {
            v2f lo = { hq[k].x, hq[k].y };
            v2f hi = { hq[k].z, hq[k].w };
            a0 += E2[2 * k] * lo;
            a1 += E2[2 * k + 1] * hi;
        }
        float d = (a0.x + a1.x) + (a0.y + a1.y);
        q = d * re;
        Clog2 += __log2f(h0);
        if (lane < NT) hs[lane] = q;
    };

    int t = 1;
    while (t + 8 <= L) {
        #pragma unroll
        for (int u = 0; u < 8; ++u) {
            STEP(fb[u]);
            int tp = t + u + 8;
            fb[u] = fbase[(size_t)(tp < SEQ ? tp : 0) * NT];
        }
        t += 8;
    }
    #pragma unroll
    for (int u = 0; u < 8; ++u)
        if (t + u < L) STEP(fb[u]);

    float term = (lane < NT) ? q * Eend : 0.0f;
    #pragma unroll
    for (int m = 32; m >= 1; m >>= 1) term += __shfl_xor(term, m, 64);
    if (lane == 0) out[b] = LN2f * (Clog2 + __log2f(term));
}

extern "C" void kernel_launch(void* const* d_in, const int* in_sizes, int n_in,
                              void* d_out, int out_size, void* d_ws, size_t ws_size,
                              hipStream_t stream) {
    const float* features    = (const float*)d_in[0];
    const float* transitions = (const float*)d_in[1];
    const int*   seqlen      = (const int*)d_in[2];
    float* out = (float*)d_out;

    const size_t need = (size_t)TW + (size_t)BATCH * 64 * 4608;   // ~75.7 MB
    if (ws_size >= need) {
        crf_setup<<<1, 64, 0, stream>>>(transitions, seqlen, d_ws);
        crf_phase1h<<<4096, 256, 0, stream>>>(features, seqlen, d_ws);
        crf_phase2s<<<BATCH, 128, 0, stream>>>(transitions, seqlen, d_ws, out);
    } else {
        crf_scalar<<<BATCH, 64, 0, stream>>>(features, transitions, seqlen, out);
    }
}

// Round 21
// 118.719 us; speedup vs baseline: 1.0447x; 1.0447x over previous
//
#include <hip/hip_runtime.h>

#define BATCH 256
#define SEQ 2048
#define NT 48
#define START_TAG 46
#define END_TAG 47
#define LN2f  0.6931471805599453f

// ws layout
#define TAF16 0        // K16 A-frags exp(trans) bf16: [9][64] x 8B  = 4608
#define TBF   4608     // B-frag exp(trans) f32: [9][64] x 16B       = 9216
#define TCUM  13824    // prefix sums: int cum[257] (cum[0]=0)       = 1028
#define TSC   16384    // per-chunk log2 scales: [B][64] f32         = 64KiB
#define TW    131072   // chunk matrices bf16: [B][64][48][48]
                       //   chunk c < h : M row-major   (left half, b <- M b)
                       //   chunk c >= h: M^T row-major (right half, u^T <- u^T M)

typedef float v2f __attribute__((ext_vector_type(2)));
typedef float v4f __attribute__((ext_vector_type(4)));
typedef short s16x4 __attribute__((ext_vector_type(4)));
typedef unsigned int u32;
typedef unsigned short u16;
typedef u32 u32x2 __attribute__((ext_vector_type(2)));
typedef u32 u32x4 __attribute__((ext_vector_type(4)));

__device__ __forceinline__ u32 pkbf(float a, float b) {
    u32 r;
    asm("v_cvt_pk_bf16_f32 %0, %1, %2" : "=v"(r) : "v"(a), "v"(b));
    return r;
}
__device__ __forceinline__ float bflo(u32 w) { return __builtin_bit_cast(float, w << 16); }
__device__ __forceinline__ float bfhi(u32 w) { return __builtin_bit_cast(float, w & 0xffff0000u); }

__device__ __forceinline__ float rfl(float x) {
    return __builtin_bit_cast(float,
        __builtin_amdgcn_readfirstlane(__builtin_bit_cast(int, x)));
}

__device__ __forceinline__ v4f mfma16_z(s16x4 a, s16x4 b, v4f z) {
    v4f d;
    asm volatile("v_mfma_f32_16x16x16_bf16 %0, %2, %3, %1"
                 : "=&v"(d) : "v"(z), "v"(a), "v"(b));
    return d;
}
__device__ __forceinline__ void mfma16_acc(v4f& acc, s16x4 a, s16x4 b) {
    asm volatile("v_mfma_f32_16x16x16_bf16 %0, %1, %2, %0"
                 : "+v"(acc) : "v"(a), "v"(b));
}

// ---------------------------------------------------------------------------
// Kernel 0: exp(trans) fragments + chunk-count prefix sums (32-step chunks).
// A-frag (I,K): lane holds E[I*16+(l&15)][K*16+(l>>4)*4+i], bf16.
// B-frag (K,J): lane holds E[K*16+(l>>4)*4+i][J*16+(l&15)], f32.
// ---------------------------------------------------------------------------
__global__ void __launch_bounds__(64)
crf_setup(const float* __restrict__ trans, const int* __restrict__ seqlen,
          void* ws) {
    __shared__ float el[NT * NT];
    const int lane = threadIdx.x, ln = lane & 15, g = lane >> 4;
    #pragma unroll
    for (int m = 0; m < 36; ++m) {
        int idx = lane + 64 * m;
        el[idx] = __expf(trans[idx]);
    }
    u32x2* AF = (u32x2*)((char*)ws + TAF16);
    v4f*   BF = (v4f*)((char*)ws + TBF);
    #pragma unroll
    for (int I = 0; I < 3; ++I)
        #pragma unroll
        for (int K = 0; K < 3; ++K) {
            const v4f ev = *(const v4f*)&el[(I * 16 + ln) * NT + K * 16 + g * 4];
            AF[(I * 3 + K) * 64 + lane] = (u32x2){pkbf(ev.x, ev.y), pkbf(ev.z, ev.w)};
        }
    #pragma unroll
    for (int K = 0; K < 3; ++K)
        #pragma unroll
        for (int J = 0; J < 3; ++J) {
            v4f v;
            #pragma unroll
            for (int i = 0; i < 4; ++i)
                v[i] = el[(K * 16 + g * 4 + i) * NT + J * 16 + ln];
            BF[(K * 3 + J) * 64 + lane] = v;
        }
    if (lane == 0) {
        int* cum = (int*)((char*)ws + TCUM);
        int acc = 0;
        for (int b = 0; b < BATCH; ++b) {
            cum[b] = acc;
            int L = seqlen[b];
            if (L < 1) L = 1;
            if (L > SEQ) L = SEQ;
            acc += (L + 31) >> 5;
        }
        cum[BATCH] = acc;
    }
}

// ---------------------------------------------------------------------------
// Kernel 1 (r13/r18-proven config): wave widx handles the widx-th ACTIVE
// 32-step chunk (binary search over cum[]).  K16 MFMA chain: acc = E*M
// (27 MFMA, 3 levels x 9, asm-pinned), gn = raw P00,
// M' = acc .* (em * 1/gn_prev), Lc += log2(gn) lagged.  Emissions pre-exp'd
// into wave-private LDS.  __launch_bounds__(256,4): cap 128 — the only
// spill-free point (r14/r16/r19: caps 64/85/102 all spill this body).
// Store format direction-aware for split phase2: c < h (h = nb/2) stored
// as M row-major, c >= h as M^T row-major.
// Ceiling note (r20): per-SIMD pipes at this operating point are ~82% busy
// (MfmaUtil 45% + VALUBusy 37%); all residency/ILP/shape levers HW-refuted.
// ---------------------------------------------------------------------------
__global__ void __launch_bounds__(256, 4)
crf_phase1c(const float* __restrict__ feat, const int* __restrict__ seqlen,
            void* __restrict__ ws) {
    const int wid = threadIdx.x >> 6;
    const int widx = blockIdx.x * 4 + wid;
    const int* cum = (const int*)((const char*)ws + TCUM);
    if (widx >= cum[BATCH]) return;

    int lo = 0, hi = BATCH;          // invariant: cum[lo] <= widx < cum[hi]
    #pragma unroll
    for (int it = 0; it < 8; ++it) {
        int mid = (lo + hi) >> 1;
        if (cum[mid] <= widx) lo = mid; else hi = mid;
    }
    const int b = lo;
    const int c = widx - cum[b];
    const int t0 = c * 32;
    int Lraw = seqlen[b];
    if (Lraw < 1) Lraw = 1;
    if (Lraw > SEQ) Lraw = SEQ;
    const int nbS = (Lraw + 31) >> 5;
    const int half = nbS >> 1;
    int n = Lraw - t0;
    if (n > 32) n = 32;

    const int lane = threadIdx.x & 63, ln = lane & 15, g = lane >> 4;

    __shared__ v4f flv[4][32 * 12];
    v4f* fl = flv[wid];

    s16x4 aw[3][3];
    {
        const u32x2* AF = (const u32x2*)((const char*)ws + TAF16);
        #pragma unroll
        for (int I = 0; I < 3; ++I)
            #pragma unroll
            for (int K = 0; K < 3; ++K)
                aw[I][K] = __builtin_bit_cast(s16x4, AF[(I * 3 + K) * 64 + lane]);
    }

    // stage rows t0..t0+31 (t0 <= 2016, in-bounds), exp() applied once
    {
        const v4f* fg = (const v4f*)(feat + ((size_t)b * SEQ + t0) * NT);
        #pragma unroll
        for (int m = 0; m < 6; ++m) {
            v4f v = fg[m * 64 + lane];
            v4f e;
            #pragma unroll
            for (int i = 0; i < 4; ++i) e[i] = __expf(v[i]);
            fl[m * 64 + lane] = e;
        }
    }

    // init M = D_{t0} E
    s16x4 mw[3][3];
    {
        const v4f* BF = (const v4f*)((const char*)ws + TBF);
        v4f em[3];
        #pragma unroll
        for (int K = 0; K < 3; ++K) em[K] = fl[K * 4 + g];
        #pragma unroll
        for (int K = 0; K < 3; ++K)
            #pragma unroll
            for (int J = 0; J < 3; ++J) {
                v4f sc = BF[(K * 3 + J) * 64 + lane] * em[K];
                mw[K][J] = __builtin_bit_cast(s16x4,
                    (u32x2){pkbf(sc.x, sc.y), pkbf(sc.z, sc.w)});
            }
    }

    float Lc = 0.f, lg = 0.f, s = 1.f;
    const v4f kz = {0.f, 0.f, 0.f, 0.f};

    for (int t = 1; t < n; ++t) {
        v4f em[3];
        #pragma unroll
        for (int K = 0; K < 3; ++K) em[K] = fl[t * 12 + K * 4 + g];

        v4f acc[3][3];
        #pragma unroll
        for (int I = 0; I < 3; ++I)
            #pragma unroll
            for (int J = 0; J < 3; ++J)
                acc[I][J] = mfma16_z(aw[I][0], mw[0][J], kz);
        #pragma unroll
        for (int I = 0; I < 3; ++I)
            #pragma unroll
            for (int J = 0; J < 3; ++J)
                mfma16_acc(acc[I][J], aw[I][1], mw[1][J]);
        #pragma unroll
        for (int I = 0; I < 3; ++I)
            #pragma unroll
            for (int J = 0; J < 3; ++J)
                mfma16_acc(acc[I][J], aw[I][2], mw[2][J]);
        asm volatile("s_nop 7\n\ts_nop 7");
        __builtin_amdgcn_sched_barrier(0);

        const float gn = rfl(acc[0][0].x);
        Lc += lg;
        #pragma unroll
        for (int K = 0; K < 3; ++K) {
            v4f sp = em[K] * s;
            #pragma unroll
            for (int J = 0; J < 3; ++J) {
                v4f sc = acc[K][J] * sp;
                mw[K][J] = __builtin_bit_cast(s16x4,
                    (u32x2){pkbf(sc.x, sc.y), pkbf(sc.z, sc.w)});
            }
        }
        lg = __log2f(gn);
        s  = __builtin_amdgcn_rcpf(gn);
    }

    // store: element M[row][col], row = K*16+g*4+i, col = J*16+ln.
    char* wb = (char*)ws + TW + ((size_t)(b * 64 + c)) * 4608;
    if (c >= half) {
        // M^T row-major (right half): byte 2*(col*48+row)
        #pragma unroll
        for (int K = 0; K < 3; ++K)
            #pragma unroll
            for (int J = 0; J < 3; ++J) {
                u32x2 w = __builtin_bit_cast(u32x2, mw[K][J]);
                *(u32*)(wb + 2 * ((J * 16 + ln) * NT + K * 16 + g * 4))     = w.x;
                *(u32*)(wb + 2 * ((J * 16 + ln) * NT + K * 16 + g * 4 + 2)) = w.y;
            }
    } else {
        // M row-major (left half): byte 2*(row*48+col)
        u16* mb = (u16*)wb;
        #pragma unroll
        for (int K = 0; K < 3; ++K)
            #pragma unroll
            for (int J = 0; J < 3; ++J) {
                u32x2 w = __builtin_bit_cast(u32x2, mw[K][J]);
                const int r0 = K * 16 + g * 4, col = J * 16 + ln;
                mb[(r0 + 0) * NT + col] = (u16)(w.x & 0xffff);
                mb[(r0 + 1) * NT + col] = (u16)(w.x >> 16);
                mb[(r0 + 2) * NT + col] = (u16)(w.y & 0xffff);
                mb[(r0 + 3) * NT + col] = (u16)(w.y >> 16);
            }
    }
    if (lane == 0)
        ((float*)((char*)ws + TSC))[b * 64 + c] = Lc;
}

// ---------------------------------------------------------------------------
// Kernel 2 (split): 128 threads per sample.  Associativity:
//   out = u0^T (M_{nb-1}..M_h) (M_{h-1}..M_0) e_START
// wave0: a^T <- a^T M_c, c = nb-1..h   (M^T rows, a0 = exp(trans[END][:]))
// wave1: b   <- M_c b,   c = 0..h-1    (M rows,   b0 = e_START)
// Both rescale by first element per hop (guarded for b0[0]=0) and track D.
// out = ln2*(Da + Db + log2(a . b)).
// ---------------------------------------------------------------------------
__global__ void __launch_bounds__(128)
crf_phase2s(const float* __restrict__ trans, const int* __restrict__ seqlen,
            const void* __restrict__ ws, float* __restrict__ out) {
    const int b = blockIdx.x;
    const int wave = threadIdx.x >> 6;
    const int lane = threadIdx.x & 63;
    const int j = (lane < NT) ? lane : (lane - 16);

    __shared__ v4f hsv[2][12];
    __shared__ float sres[2][NT];
    __shared__ float sD[2];
    float* hs = (float*)hsv[wave];

    int L = seqlen[b];
    if (L < 1) L = 1;
    if (L > SEQ) L = SEQ;
    const int nb = (L + 31) >> 5;
    const int half = nb >> 1;
    const float* sc = (const float*)((const char*)ws + TSC) + b * 64;
    const char* wbase = (const char*)ws + TW + (size_t)b * 64 * 4608;

    // per-wave chunk range and direction
    const int c0   = wave ? 0 : (nb - 1);      // first chunk
    const int cstep = wave ? 1 : -1;
    const int nhops = wave ? half : (nb - half);

    float q = wave ? ((j == START_TAG) ? 1.f : 0.f)
                   : __expf(trans[END_TAG * NT + j]);
    float D = 0.f;

    if (nhops > 0) {
        u32x4 buf[6];
        {
            const u32x4* wr = (const u32x4*)(wbase + (size_t)c0 * 4608 + j * 96);
            #pragma unroll
            for (int m = 0; m < 6; ++m) buf[m] = wr[m];
        }
        for (int hh = 0; hh < nhops; ++hh) {
            const int c = c0 + hh * cstep;
            u32x4 cur[6];
            #pragma unroll
            for (int m = 0; m < 6; ++m) cur[m] = buf[m];
            if (hh + 1 < nhops) {
                const u32x4* wr =
                    (const u32x4*)(wbase + (size_t)(c + cstep) * 4608 + j * 96);
                #pragma unroll
                for (int m = 0; m < 6; ++m) buf[m] = wr[m];
            }

            if (lane < NT) hs[lane] = q;
            v4f hq[12];
            #pragma unroll
            for (int k = 0; k < 12; ++k) hq[k] = hsv[wave][k];
            const float h0 = hq[0][0];

            v2f a = {0.f, 0.f};
            #pragma unroll
            for (int m = 0; m < 6; ++m) {
                #pragma unroll
                for (int p = 0; p < 4; ++p) {
                    const int i = 2 * (4 * m + p);
                    u32 wv = cur[m][p];
                    v2f wp;
                    wp.x = bflo(wv);
                    wp.y = bfhi(wv);
                    v2f up = { hq[i >> 2][i & 3], hq[i >> 2][(i & 3) + 1] };
                    a += wp * up;
                }
            }
            const float dot = a.x + a.y;
            const bool ok = (h0 > 0.f);
            q = ok ? dot * __builtin_amdgcn_rcpf(h0) : dot;
            D += (ok ? __log2f(h0) : 0.f) + sc[c];
        }
    }

    if (lane < NT) sres[wave][j] = q;
    if (lane == 0) sD[wave] = D;
    __syncthreads();

    if (wave == 0) {
        float term = (lane < NT) ? sres[0][lane] * sres[1][lane] : 0.f;
        #pragma unroll
        for (int m = 32; m >= 1; m >>= 1) term += __shfl_xor(term, m, 64);
        if (lane == 0)
            out[b] = LN2f * (sD[0] + sD[1] + __log2f(term));
    }
}

// ---------------------------------------------------------------------------
// Fallback: proven round-2 scalar kernel (ws too small)
// ---------------------------------------------------------------------------
__global__ void __launch_bounds__(64)
crf_scalar(const float* __restrict__ features, const float* __restrict__ transitions,
           const int* __restrict__ seq_len, float* __restrict__ out) {
    const int b = blockIdx.x;
    const int lane = threadIdx.x;
    const int j = (lane < NT) ? lane : (lane - 16);
    __shared__ v4f hs4[NT / 4];
    float* hs = (float*)hs4;

    v2f E2[NT / 2];
    {
        const v4f* trow = (const v4f*)(transitions + j * NT);
        #pragma unroll
        for (int k = 0; k < NT / 4; ++k) {
            v4f tv = trow[k];
            E2[2 * k].x = __expf(tv.x); E2[2 * k].y = __expf(tv.y);
            E2[2 * k + 1].x = __expf(tv.z); E2[2 * k + 1].y = __expf(tv.w);
        }
    }
    const float Eend = __expf(transitions[END_TAG * NT + j]);
    const int L = seq_len[b];
    const float* fbase = features + ((size_t)b * SEQ) * NT + j;

    float q = E2[START_TAG / 2].x * __expf(fbase[0]);
    float Clog2 = 0.0f;
    if (lane < NT) hs[lane] = q;

    float fb[8];
    #pragma unroll
    for (int u = 0; u < 8; ++u) {
        int tp = 1 + u;
        fb[u] = fbase[(size_t)(tp < SEQ ? tp : 0) * NT];
    }

    auto STEP = [&](float femit) {
        v4f hq[NT / 4];
        #pragma unroll
        for (int k = 0; k < NT / 4; ++k) hq[k] = hs4[k];
        float h0 = hq[0].x;
        float r = __builtin_amdgcn_rcpf(h0);
        float e = __expf(femit);
        float re = r * e;
        v2f a0 = {0.f, 0.f}, a1 = {0.f, 0.f};
        #pragma unroll
        for (int k = 0; k < NT / 4; ++k) {
            v2f lo = { hq[k].x, hq[k].y };
            v2f hi = { hq[k].z, hq[k].w };
            a0 += E2[2 * k] * lo;
            a1 += E2[2 * k + 1] * hi;
        }
        float d = (a0.x + a1.x) + (a0.y + a1.y);
        q = d * re;
        Clog2 += __log2f(h0);
        if (lane < NT) hs[lane] = q;
    };

    int t = 1;
    while (t + 8 <= L) {
        #pragma unroll
        for (int u = 0; u < 8; ++u) {
            STEP(fb[u]);
            int tp = t + u + 8;
            fb[u] = fbase[(size_t)(tp < SEQ ? tp : 0) * NT];
        }
        t += 8;
    }
    #pragma unroll
    for (int u = 0; u < 8; ++u)
        if (t + u < L) STEP(fb[u]);

    float term = (lane < NT) ? q * Eend : 0.0f;
    #pragma unroll
    for (int m = 32; m >= 1; m >>= 1) term += __shfl_xor(term, m, 64);
    if (lane == 0) out[b] = LN2f * (Clog2 + __log2f(term));
}

extern "C" void kernel_launch(void* const* d_in, const int* in_sizes, int n_in,
                              void* d_out, int out_size, void* d_ws, size_t ws_size,
                              hipStream_t stream) {
    const float* features    = (const float*)d_in[0];
    const float* transitions = (const float*)d_in[1];
    const int*   seqlen      = (const int*)d_in[2];
    float* out = (float*)d_out;

    const size_t need = (size_t)TW + (size_t)BATCH * 64 * 4608;   // ~75.7 MB
    if (ws_size >= need) {
        crf_setup<<<1, 64, 0, stream>>>(transitions, seqlen, d_ws);
        crf_phase1c<<<4096, 256, 0, stream>>>(features, seqlen, d_ws);
        crf_phase2s<<<BATCH, 128, 0, stream>>>(transitions, seqlen, d_ws, out);
    } else {
        crf_scalar<<<BATCH, 64, 0, stream>>>(features, transitions, seqlen, out);
    }
}